// Round 19
// baseline (14354.779 us; speedup 1.0000x reference)
//
#include <hip/hip_runtime.h>
#include <math.h>

#define B_   64
#define S_   512
#define IN_  512
#define H_   1024
#define WLK_ (H_ + 128)
#define NBLK 256
#define NTHR 1024

typedef unsigned long long ull;
typedef int   i32x4 __attribute__((ext_vector_type(4)));
typedef float f32x4 __attribute__((ext_vector_type(4)));

// CK-style raw buffer load intrinsic (compiler-scheduled, vmcnt-tracked).
// cachepolicy=16 -> SC1: device-scope, MALL-served (R8/R16-proven coherent).
__device__ f32x4 llvm_amdgcn_raw_buffer_load_v4f32(i32x4 srsrc, int voffset,
                                                   int soffset, int cachepolicy)
    __asm("llvm.amdgcn.raw.buffer.load.v4f32");

__device__ __forceinline__ i32x4 mkrsrc(const void* p) {
    union { const void* p; unsigned u[2]; } a; a.p = p;
    i32x4 r;
    r.x = (int)a.u[0];
    r.y = (int)a.u[1];
    r.z = -1;
    r.w = 0x00020000;
    return r;
}

// ---- static device scratch ----
__device__ float g_xT[(size_t)S_ * IN_ * B_];   // [s][k][b]
__device__ float g_h0T[H_ * B_];                // [k][b]
__device__ float g_hT[2][H_ * B_];              // [k][b]  (coherent)
__device__ float g_hhatT[H_ * B_];              // [j][b]  (coherent)
__device__ float g_zprojT[H_ * B_];             // [j][b] includes b_lin
__device__ unsigned g_bar[2 * S_][2048];        // 64 counters/slot, 128B apart

// TLP probe: R18 structure at 1024 thr/block (16 waves/CU = 4/SIMD), 16B sc1
// loads, 16 reqs/thread/phase. Tests per-wave-outstanding vs CU-queue limit.
// LESSONS: weight composition fatal (R13); named-reg asm pipelines spill
// (R8/R9); cross-CU plain-load staging races (R11); batch-split loses to L2
// weight streams + conflicts (R14/R17).
__device__ __forceinline__ void coh_store2(float* p, float x, float y) {
    union { float2 f; ull u; } v; v.f = make_float2(x, y);
    __hip_atomic_store((ull*)p, v.u, __ATOMIC_RELAXED, __HIP_MEMORY_SCOPE_AGENT);
}

// ---------------- prologue 1: transpose inputs [B][S][IN] -> xT [S][IN][B] ----
__global__ void pre_transpose_x(const float* __restrict__ in) {
    __shared__ float lds[64][65];
    int s  = blockIdx.x >> 3;
    int k0 = (blockIdx.x & 7) << 6;
    int tid = threadIdx.x;
    int kk = tid & 63, bq = tid >> 6;
    for (int b = bq; b < 64; b += 4)
        lds[kk][b] = in[((size_t)b * S_ + s) * IN_ + k0 + kk];
    __syncthreads();
    int bb = tid & 63, kq = tid >> 6;
    for (int k = kq; k < 64; k += 4)
        g_xT[((size_t)s * IN_ + k0 + k) * B_ + bb] = lds[k][bb];
}

// ---------------- prologue 2: z_projT (incl b_lin), h0T, zero barriers ------
__global__ void pre_misc(const float* __restrict__ z, const float* __restrict__ Wlin,
                         const float* __restrict__ blin, const float* __restrict__ h0) {
    __shared__ float zT[128][65];
    int j = blockIdx.x;      // 0..1023 == 2*S_ rows exactly
    int b = threadIdx.x;     // 0..63
    for (int i = 0; i < 128; ++i) {
        int idx = b + (i << 6);
        zT[idx & 127][idx >> 7] = z[idx];
    }
    __syncthreads();
    float acc = blin[j];
    const float* w = Wlin + (size_t)j * WLK_ + H_;
    for (int k = 0; k < 128; ++k)
        acc = fmaf(zT[k][b], w[k], acc);
    g_zprojT[j * 64 + b] = acc;
    g_h0T[j * 64 + b]    = h0[(size_t)b * H_ + j];
    for (int i = b; i < 2048; i += 64)
        g_bar[j][i] = 0;
}

#define F4(AC, WS) AC.x=fmaf(WS,a.x,AC.x); AC.y=fmaf(WS,a.y,AC.y); AC.z=fmaf(WS,a.z,AC.z); AC.w=fmaf(WS,a.w,AC.w);

// 12-col GEMM over K=512, plain cached loads (read-only x) — for gi(0)
__device__ __forceinline__ void gemm12n(const float* __restrict__ src,
                                        const float* wl,
                                        const float* bias_l, float* dst,
                                        float* red, int tid) {
    const int bq = tid & 15, kq = tid >> 4;   // kq 0..63
    const int wv = tid >> 6, ln = tid & 63;
    const float* ap = src + (kq << 6) + (bq << 2);
    const float* wp = wl + kq * 12;
    f32x4 acc[12];
    #pragma unroll
    for (int c = 0; c < 12; ++c) acc[c] = (f32x4){0.f,0.f,0.f,0.f};
    #pragma unroll 4
    for (int i = 0; i < 8; ++i) {
        f32x4 a  = *(const f32x4*)ap;  ap += 64 * 64;
        f32x4 w0 = *(const f32x4*)(wp + 0);
        f32x4 w1 = *(const f32x4*)(wp + 4);
        f32x4 w2 = *(const f32x4*)(wp + 8);  wp += 64 * 12;
        F4(acc[0],w0.x) F4(acc[1],w0.y) F4(acc[2],w0.z)  F4(acc[3],w0.w)
        F4(acc[4],w1.x) F4(acc[5],w1.y) F4(acc[6],w1.z)  F4(acc[7],w1.w)
        F4(acc[8],w2.x) F4(acc[9],w2.y) F4(acc[10],w2.z) F4(acc[11],w2.w)
    }
    #pragma unroll
    for (int c = 0; c < 12; ++c) {
        f32x4 v = acc[c];
        v.x += __shfl_xor(v.x,16); v.y += __shfl_xor(v.y,16);
        v.z += __shfl_xor(v.z,16); v.w += __shfl_xor(v.w,16);
        v.x += __shfl_xor(v.x,32); v.y += __shfl_xor(v.y,32);
        v.z += __shfl_xor(v.z,32); v.w += __shfl_xor(v.w,32);
        if (ln < 16) *(f32x4*)&red[(wv * 12 + c) * 64 + (ln << 2)] = v;
    }
    __syncthreads();
    if (tid < 768) {
        int c = tid >> 6, b = tid & 63;
        float s = bias_l[c];
        #pragma unroll
        for (int w = 0; w < 16; ++w) s += red[(w * 12 + c) * 64 + b];
        dst[tid] = s;
    }
}

// 12-col GEMM over K=1024, 16B sc1 buffer loads — for P2
__device__ __forceinline__ void gemm12b(i32x4 rsrc, const float* wl,
                                        const float* bias_l, float* dst,
                                        float* red, int tid) {
    const int bq = tid & 15, kq = tid >> 4;   // kq 0..63
    const int wv = tid >> 6, ln = tid & 63;
    int voff = ((kq << 6) + (bq << 2)) << 2;
    const float* wp = wl + kq * 12;
    f32x4 acc[12];
    #pragma unroll
    for (int c = 0; c < 12; ++c) acc[c] = (f32x4){0.f,0.f,0.f,0.f};
    #pragma unroll 8
    for (int i = 0; i < 16; ++i) {
        f32x4 a = llvm_amdgcn_raw_buffer_load_v4f32(rsrc, voff, 0, 16);
        voff += 64 * 64 * 4;
        f32x4 w0 = *(const f32x4*)(wp + 0);
        f32x4 w1 = *(const f32x4*)(wp + 4);
        f32x4 w2 = *(const f32x4*)(wp + 8);  wp += 64 * 12;
        F4(acc[0],w0.x) F4(acc[1],w0.y) F4(acc[2],w0.z)  F4(acc[3],w0.w)
        F4(acc[4],w1.x) F4(acc[5],w1.y) F4(acc[6],w1.z)  F4(acc[7],w1.w)
        F4(acc[8],w2.x) F4(acc[9],w2.y) F4(acc[10],w2.z) F4(acc[11],w2.w)
    }
    #pragma unroll
    for (int c = 0; c < 12; ++c) {
        f32x4 v = acc[c];
        v.x += __shfl_xor(v.x,16); v.y += __shfl_xor(v.y,16);
        v.z += __shfl_xor(v.z,16); v.w += __shfl_xor(v.w,16);
        v.x += __shfl_xor(v.x,32); v.y += __shfl_xor(v.y,32);
        v.z += __shfl_xor(v.z,32); v.w += __shfl_xor(v.w,32);
        if (ln < 16) *(f32x4*)&red[(wv * 12 + c) * 64 + (ln << 2)] = v;
    }
    __syncthreads();
    if (tid < 768) {
        int c = tid >> 6, b = tid & 63;
        float s = bias_l[c];
        #pragma unroll
        for (int w = 0; w < 16; ++w) s += red[(w * 12 + c) * 64 + b];
        dst[tid] = s;
    }
}

// NC-col slice (cols C0..C0+NC-1), K=512 plain loads — per-col bit-identical
// to gemm12n; splits gi across the two barrier-hidden slots.
template<int NC, int C0>
__device__ __forceinline__ void gemmN(const float* __restrict__ src,
                                      const float* wl,
                                      const float* bias_l, float* dst,
                                      float* red, int tid) {
    const int bq = tid & 15, kq = tid >> 4;   // kq 0..63
    const int wv = tid >> 6, ln = tid & 63;
    const float* ap = src + (kq << 6) + (bq << 2);
    const float* wp = wl + kq * 12 + C0;
    f32x4 acc[NC];
    #pragma unroll
    for (int c = 0; c < NC; ++c) acc[c] = (f32x4){0.f,0.f,0.f,0.f};
    #pragma unroll 4
    for (int i = 0; i < 8; ++i) {
        f32x4 a = *(const f32x4*)ap;  ap += 64 * 64;
        #pragma unroll
        for (int g = 0; g < NC / 4; ++g) {
            f32x4 w = *(const f32x4*)(wp + 4 * g);
            F4(acc[4*g+0],w.x) F4(acc[4*g+1],w.y) F4(acc[4*g+2],w.z) F4(acc[4*g+3],w.w)
        }
        wp += 64 * 12;
    }
    #pragma unroll
    for (int c = 0; c < NC; ++c) {
        f32x4 v = acc[c];
        v.x += __shfl_xor(v.x,16); v.y += __shfl_xor(v.y,16);
        v.z += __shfl_xor(v.z,16); v.w += __shfl_xor(v.w,16);
        v.x += __shfl_xor(v.x,32); v.y += __shfl_xor(v.y,32);
        v.z += __shfl_xor(v.z,32); v.w += __shfl_xor(v.w,32);
        if (ln < 16) *(f32x4*)&red[(wv * NC + c) * 64 + (ln << 2)] = v;
    }
    __syncthreads();
    if (tid < NC * 64) {
        int c = tid >> 6, b = tid & 63;
        float s = bias_l[C0 + c];
        #pragma unroll
        for (int w = 0; w < 16; ++w) s += red[(w * NC + c) * 64 + b];
        dst[(C0 + c) * 64 + b] = s;
    }
}

// global barrier wait: wave 0 polls all 64 counters in parallel, __all exit
__device__ __forceinline__ void gbar_wait(int slot, int tid) {
    if (tid < 64) {
        for (;;) {
            unsigned c = __hip_atomic_load(&g_bar[slot][tid << 5],
                                           __ATOMIC_RELAXED, __HIP_MEMORY_SCOPE_AGENT);
            if (__all(c >= 4u)) break;
            __builtin_amdgcn_s_sleep(1);
        }
    }
    __syncthreads();
    asm volatile("" ::: "memory");
}

// ---------------- persistent recurrence kernel ------------------------------
// 256 blocks x 1024 threads (16 waves/CU = 4/SIMD); block owns cols 4*blk..+3.
// P1 h_hat | arrive A | gi cols 0-7 | wait A | P2 gh + gates | arrive B |
// out-write + gi cols 8-11 | wait B.
__launch_bounds__(NTHR, 1)
__global__ void skipgru_2ph(const float* __restrict__ Wlin, const float* __restrict__ Wih,
                            const float* __restrict__ bih,  const float* __restrict__ Whh,
                            const float* __restrict__ bhh,  float* __restrict__ out) {
    __shared__ float wA[H_ * 4];         // 16 KB [k][c<4]
    __shared__ float wB[H_ * 12];        // 48 KB [k][c<12]
    __shared__ float wX[IN_ * 12];       // 24 KB [k][c<12]
    __shared__ float red[16 * 12 * 64];  // 48 KB
    __shared__ float gh_l[12 * 64];
    __shared__ float gi_a[12 * 64];
    __shared__ float gi_b[12 * 64];
    __shared__ float hh_l[4 * 64];
    __shared__ float hn_l[4 * 64];
    __shared__ float zp_l[4 * 64];
    __shared__ float bhh_l[12];
    __shared__ float bih_l[12];

    const int tid = threadIdx.x;
    const int jb  = blockIdx.x << 2;
    const int bq  = tid & 15;
    const int kq  = tid >> 4;            // 0..63
    const int wv  = tid >> 6, ln = tid & 63;
    const int barctr = (blockIdx.x & 63) << 5;   // 64 counters, 128 B apart

    for (int c = 0; c < 4; ++c) {
        const float* src = Wlin + (size_t)(jb + c) * WLK_;
        for (int k = tid; k < H_; k += NTHR) wA[k * 4 + c] = src[k];
    }
    for (int c = 0; c < 12; ++c) {
        const float* src = Whh + (size_t)((c >> 2) * H_ + jb + (c & 3)) * H_;
        for (int k = tid; k < H_; k += NTHR) wB[k * 12 + c] = src[k];
    }
    for (int c = 0; c < 12; ++c) {
        const float* src = Wih + (size_t)((c >> 2) * H_ + jb + (c & 3)) * IN_;
        for (int k = tid; k < IN_; k += NTHR) wX[k * 12 + c] = src[k];
    }
    if (tid < 256) zp_l[tid] = g_zprojT[(jb + (tid >> 6)) * 64 + (tid & 63)];
    if (tid < 12) {
        bhh_l[tid] = bhh[(tid >> 2) * H_ + jb + (tid & 3)];
        bih_l[tid] = bih[(tid >> 2) * H_ + jb + (tid & 3)];
    }
    __syncthreads();

    gemm12n(g_xT, wX, bih_l, gi_a, red, tid);
    __syncthreads();

    const i32x4 rs_hhat = mkrsrc(g_hhatT);
    const i32x4 rs_h0   = mkrsrc(g_h0T);
    const i32x4 rs_ha   = mkrsrc(g_hT[0]);
    const i32x4 rs_hb   = mkrsrc(g_hT[1]);

    for (int t = 0; t < S_; ++t) {
        const i32x4 rs_h = (t == 0) ? rs_h0 : ((t & 1) ? rs_hb : rs_ha);
        const float* gi_cur = (t & 1) ? gi_b : gi_a;
        float*       gi_nxt = (t & 1) ? gi_a : gi_b;
        const float* xnxt = g_xT + (size_t)(t + 1) * IN_ * B_;

        // ---- P1: h_hat, 4 cols, K=1024 (16B sc1 loads, 16 reqs/thread) ----
        {
            int voff = ((kq << 6) + (bq << 2)) << 2;
            const float* wp = wA + kq * 4;
            f32x4 acc[4];
            #pragma unroll
            for (int c = 0; c < 4; ++c) acc[c] = (f32x4){0.f,0.f,0.f,0.f};
            #pragma unroll 8
            for (int i = 0; i < 16; ++i) {
                f32x4 a = llvm_amdgcn_raw_buffer_load_v4f32(rs_h, voff, 0, 16);
                voff += 16384;
                f32x4 w = *(const f32x4*)wp;  wp += 64 * 4;
                F4(acc[0],w.x) F4(acc[1],w.y) F4(acc[2],w.z) F4(acc[3],w.w)
            }
            #pragma unroll
            for (int c = 0; c < 4; ++c) {
                f32x4 v = acc[c];
                v.x += __shfl_xor(v.x,16); v.y += __shfl_xor(v.y,16);
                v.z += __shfl_xor(v.z,16); v.w += __shfl_xor(v.w,16);
                v.x += __shfl_xor(v.x,32); v.y += __shfl_xor(v.y,32);
                v.z += __shfl_xor(v.z,32); v.w += __shfl_xor(v.w,32);
                if (ln < 16) *(f32x4*)&red[(wv * 4 + c) * 64 + (ln << 2)] = v;
            }
        }
        __syncthreads();
        if (tid < 256) {
            int c = tid >> 6, b = tid & 63;
            float s = zp_l[tid];
            #pragma unroll
            for (int w = 0; w < 16; ++w) s += red[(w * 4 + c) * 64 + b];
            hh_l[tid] = s;
        }
        __syncthreads();
        if (tid < 128) {
            int c = tid >> 5, pb = (tid & 31) << 1;
            coh_store2(&g_hhatT[(jb + c) * 64 + pb], hh_l[(c << 6) + pb], hh_l[(c << 6) + pb + 1]);
        }
        __syncthreads();   // vmcnt(0) drain: h_hat publish complete before arrive

        // ---- arrive A ----
        if (tid == 0)
            __hip_atomic_fetch_add(&g_bar[2 * t][barctr], 1u, __ATOMIC_RELAXED, __HIP_MEMORY_SCOPE_AGENT);

        // ---- gi(t+1) cols 0-7, hidden under barrier A ----
        if (t + 1 < S_)
            gemmN<8, 0>(xnxt, wX, bih_l, gi_nxt, red, tid);

        // ---- wait A ----
        gbar_wait(2 * t, tid);

        // ---- P2: gh, 12 cols over h_hat, K=1024 (16B sc1) ----
        gemm12b(rs_hhat, wB, bhh_l, gh_l, red, tid);
        __syncthreads();

        // ---- gates (threads 0..255) ----
        if (tid < 256) {
            int cc = tid >> 6, b = tid & 63;
            float hh = hh_l[tid];
            float hr = gh_l[cc * 64 + b];
            float hz = gh_l[(4 + cc) * 64 + b];
            float hn = gh_l[(8 + cc) * 64 + b];
            float ir = gi_cur[cc * 64 + b];
            float iz = gi_cur[(4 + cc) * 64 + b];
            float in_ = gi_cur[(8 + cc) * 64 + b];
            float r = 1.f / (1.f + expf(-(ir + hr)));
            float u = 1.f / (1.f + expf(-(iz + hz)));
            float n = tanhf(in_ + r * hn);
            float v = (1.f - u) * n + u * hh;
            hn_l[tid] = v;
        }
        __syncthreads();
        if (tid < 128) {
            int c = tid >> 5, pb = (tid & 31) << 1;
            coh_store2(&g_hT[(t + 1) & 1][(jb + c) * 64 + pb], hn_l[(c << 6) + pb], hn_l[(c << 6) + pb + 1]);
        }
        __syncthreads();   // vmcnt(0) drain: h publish complete before arrive

        // ---- arrive B ----
        if (tid == 0)
            __hip_atomic_fetch_add(&g_bar[2 * t + 1][barctr], 1u, __ATOMIC_RELAXED, __HIP_MEMORY_SCOPE_AGENT);

        // ---- out write + gi(t+1) cols 8-11, hidden under barrier B ----
        if (tid < 256) {
            int cc = tid >> 6, b = tid & 63;
            int j = jb + cc;
            float v = hn_l[tid];
            out[((size_t)b * S_ + t) * H_ + j] = v;
            if (t == S_ - 1)
                out[(size_t)B_ * S_ * H_ + (size_t)b * H_ + j] = v;
        }
        if (t + 1 < S_)
            gemmN<4, 8>(xnxt, wX, bih_l, gi_nxt, red, tid);

        // ---- wait B ----
        gbar_wait(2 * t + 1, tid);
    }
}

extern "C" void kernel_launch(void* const* d_in, const int* in_sizes, int n_in,
                              void* d_out, int out_size, void* d_ws, size_t ws_size,
                              hipStream_t stream) {
    const float* inputs = (const float*)d_in[0];
    const float* h0     = (const float*)d_in[1];
    const float* z      = (const float*)d_in[2];
    const float* Wlin   = (const float*)d_in[3];
    const float* blin   = (const float*)d_in[4];
    const float* Wih    = (const float*)d_in[5];
    const float* bih    = (const float*)d_in[6];
    const float* Whh    = (const float*)d_in[7];
    const float* bhh    = (const float*)d_in[8];
    float* out = (float*)d_out;

    hipLaunchKernelGGL(pre_transpose_x, dim3(S_ * 8), dim3(256), 0, stream, inputs);
    hipLaunchKernelGGL(pre_misc, dim3(H_), dim3(64), 0, stream, z, Wlin, blin, h0);
    hipLaunchKernelGGL(skipgru_2ph, dim3(NBLK), dim3(NTHR), 0, stream,
                       Wlin, Wih, bih, Whh, bhh, out);
}

// Round 21
// 9242.603 us; speedup vs baseline: 1.5531x; 1.5531x over previous
//
#include <hip/hip_runtime.h>
#include <math.h>

#define B_   64
#define S_   512
#define IN_  512
#define H_   1024
#define WLK_ (H_ + 128)
#define NBLK 256
#define NTHR 512

typedef unsigned long long ull;
typedef int   i32x4 __attribute__((ext_vector_type(4)));
typedef float f32x4 __attribute__((ext_vector_type(4)));

// CK-style raw buffer load intrinsic (compiler-scheduled, vmcnt-tracked).
// cachepolicy=16 -> SC1: device-scope, MALL-served (R8/R16-proven coherent).
__device__ f32x4 llvm_amdgcn_raw_buffer_load_v4f32(i32x4 srsrc, int voffset,
                                                   int soffset, int cachepolicy)
    __asm("llvm.amdgcn.raw.buffer.load.v4f32");

__device__ __forceinline__ i32x4 mkrsrc(const void* p) {
    union { const void* p; unsigned u[2]; } a; a.p = p;
    i32x4 r;
    r.x = (int)a.u[0];
    r.y = (int)a.u[1];
    r.z = -1;
    r.w = 0x00020000;
    return r;
}

// ---- static device scratch ----
__device__ float g_xT[(size_t)S_ * IN_ * B_];   // [s][k][b]
__device__ float g_h0T[H_ * B_];                // [k][b]
__device__ float g_hT[2][H_ * B_];              // [k][b]  (coherent)
__device__ float g_hhatT[H_ * B_];              // [j][b]  (coherent)
__device__ float g_zprojT[H_ * B_];             // [j][b] includes b_lin
__device__ unsigned g_bar[2 * S_][2048];        // 64 counters/slot, 128B apart

// NUMERICS LAW (R13, R20): the recurrence amplifies ANY association change
// by ~2.5e4 -> only bit-identical per-column arithmetic (the R5 association)
// passes reliably. All remaining opts must be transport/sync-only.
// LESSONS: named-reg asm pipelines spill (R8/R9); plain-load cross-CU staging
// races (R11); more waves hurt (R12/R19); batch-split side costs (R14/R17);
// K-split breaks numerics (R20). This round: R18 + fused 4B coherent publish
// (drops one syncthreads before each arrive). Stored values bit-identical.
__device__ __forceinline__ void coh_store1(float* p, float x) {
    union { float f; unsigned u; } v; v.f = x;
    __hip_atomic_store((unsigned*)p, v.u, __ATOMIC_RELAXED, __HIP_MEMORY_SCOPE_AGENT);
}

// ---------------- prologue 1: transpose inputs [B][S][IN] -> xT [S][IN][B] ----
__global__ void pre_transpose_x(const float* __restrict__ in) {
    __shared__ float lds[64][65];
    int s  = blockIdx.x >> 3;
    int k0 = (blockIdx.x & 7) << 6;
    int tid = threadIdx.x;
    int kk = tid & 63, bq = tid >> 6;
    for (int b = bq; b < 64; b += 4)
        lds[kk][b] = in[((size_t)b * S_ + s) * IN_ + k0 + kk];
    __syncthreads();
    int bb = tid & 63, kq = tid >> 6;
    for (int k = kq; k < 64; k += 4)
        g_xT[((size_t)s * IN_ + k0 + k) * B_ + bb] = lds[k][bb];
}

// ---------------- prologue 2: z_projT (incl b_lin), h0T, zero barriers ------
__global__ void pre_misc(const float* __restrict__ z, const float* __restrict__ Wlin,
                         const float* __restrict__ blin, const float* __restrict__ h0) {
    __shared__ float zT[128][65];
    int j = blockIdx.x;      // 0..1023 == 2*S_ rows exactly
    int b = threadIdx.x;     // 0..63
    for (int i = 0; i < 128; ++i) {
        int idx = b + (i << 6);
        zT[idx & 127][idx >> 7] = z[idx];
    }
    __syncthreads();
    float acc = blin[j];
    const float* w = Wlin + (size_t)j * WLK_ + H_;
    for (int k = 0; k < 128; ++k)
        acc = fmaf(zT[k][b], w[k], acc);
    g_zprojT[j * 64 + b] = acc;
    g_h0T[j * 64 + b]    = h0[(size_t)b * H_ + j];
    for (int i = b; i < 2048; i += 64)
        g_bar[j][i] = 0;
}

#define F4(AC, WS) AC.x=fmaf(WS,a.x,AC.x); AC.y=fmaf(WS,a.y,AC.y); AC.z=fmaf(WS,a.z,AC.z); AC.w=fmaf(WS,a.w,AC.w);

// 12-col GEMM over K=512, plain cached loads (read-only x) — for gi(0)
__device__ __forceinline__ void gemm12n(const float* __restrict__ src,
                                        const float* wl,
                                        const float* bias_l, float* dst,
                                        float* red, int tid) {
    const int bq = tid & 15, kq = tid >> 4;
    const int wv = tid >> 6, ln = tid & 63;
    const float* ap = src + (kq << 6) + (bq << 2);
    const float* wp = wl + kq * 12;
    f32x4 acc[12];
    #pragma unroll
    for (int c = 0; c < 12; ++c) acc[c] = (f32x4){0.f,0.f,0.f,0.f};
    #pragma unroll 4
    for (int i = 0; i < 16; ++i) {
        f32x4 a  = *(const f32x4*)ap;  ap += 32 * 64;
        f32x4 w0 = *(const f32x4*)(wp + 0);
        f32x4 w1 = *(const f32x4*)(wp + 4);
        f32x4 w2 = *(const f32x4*)(wp + 8);  wp += 32 * 12;
        F4(acc[0],w0.x) F4(acc[1],w0.y) F4(acc[2],w0.z)  F4(acc[3],w0.w)
        F4(acc[4],w1.x) F4(acc[5],w1.y) F4(acc[6],w1.z)  F4(acc[7],w1.w)
        F4(acc[8],w2.x) F4(acc[9],w2.y) F4(acc[10],w2.z) F4(acc[11],w2.w)
    }
    #pragma unroll
    for (int c = 0; c < 12; ++c) {
        f32x4 v = acc[c];
        v.x += __shfl_xor(v.x,16); v.y += __shfl_xor(v.y,16);
        v.z += __shfl_xor(v.z,16); v.w += __shfl_xor(v.w,16);
        v.x += __shfl_xor(v.x,32); v.y += __shfl_xor(v.y,32);
        v.z += __shfl_xor(v.z,32); v.w += __shfl_xor(v.w,32);
        if (ln < 16) *(f32x4*)&red[(wv * 12 + c) * 64 + (ln << 2)] = v;
    }
    __syncthreads();
    for (int o = tid; o < 768; o += NTHR) {
        int c = o >> 6, b = o & 63;
        float s = bias_l[c];
        #pragma unroll
        for (int w = 0; w < 8; ++w) s += red[(w * 12 + c) * 64 + b];
        dst[o] = s;
    }
}

// 12-col GEMM over K=1024, 16B sc1 buffer loads — unroll 8 (deep pipeline)
__device__ __forceinline__ void gemm12b(i32x4 rsrc, const float* wl,
                                        const float* bias_l, float* dst,
                                        float* red, int tid) {
    const int bq = tid & 15, kq = tid >> 4;
    const int wv = tid >> 6, ln = tid & 63;
    int voff = ((kq << 6) + (bq << 2)) << 2;
    const float* wp = wl + kq * 12;
    f32x4 acc[12];
    #pragma unroll
    for (int c = 0; c < 12; ++c) acc[c] = (f32x4){0.f,0.f,0.f,0.f};
    #pragma unroll 8
    for (int i = 0; i < 32; ++i) {
        f32x4 a = llvm_amdgcn_raw_buffer_load_v4f32(rsrc, voff, 0, 16);
        voff += 32 * 64 * 4;
        f32x4 w0 = *(const f32x4*)(wp + 0);
        f32x4 w1 = *(const f32x4*)(wp + 4);
        f32x4 w2 = *(const f32x4*)(wp + 8);  wp += 32 * 12;
        F4(acc[0],w0.x) F4(acc[1],w0.y) F4(acc[2],w0.z)  F4(acc[3],w0.w)
        F4(acc[4],w1.x) F4(acc[5],w1.y) F4(acc[6],w1.z)  F4(acc[7],w1.w)
        F4(acc[8],w2.x) F4(acc[9],w2.y) F4(acc[10],w2.z) F4(acc[11],w2.w)
    }
    #pragma unroll
    for (int c = 0; c < 12; ++c) {
        f32x4 v = acc[c];
        v.x += __shfl_xor(v.x,16); v.y += __shfl_xor(v.y,16);
        v.z += __shfl_xor(v.z,16); v.w += __shfl_xor(v.w,16);
        v.x += __shfl_xor(v.x,32); v.y += __shfl_xor(v.y,32);
        v.z += __shfl_xor(v.z,32); v.w += __shfl_xor(v.w,32);
        if (ln < 16) *(f32x4*)&red[(wv * 12 + c) * 64 + (ln << 2)] = v;
    }
    __syncthreads();
    for (int o = tid; o < 768; o += NTHR) {
        int c = o >> 6, b = o & 63;
        float s = bias_l[c];
        #pragma unroll
        for (int w = 0; w < 8; ++w) s += red[(w * 12 + c) * 64 + b];
        dst[o] = s;
    }
}

// NC-col slice (cols C0..C0+NC-1), K=512 plain loads — bit-identical per-col
// to gemm12n; used to split gi across the two barrier-hidden slots.
template<int NC, int C0>
__device__ __forceinline__ void gemmN(const float* __restrict__ src,
                                      const float* wl,
                                      const float* bias_l, float* dst,
                                      float* red, int tid) {
    const int bq = tid & 15, kq = tid >> 4;
    const int wv = tid >> 6, ln = tid & 63;
    const float* ap = src + (kq << 6) + (bq << 2);
    const float* wp = wl + kq * 12 + C0;
    f32x4 acc[NC];
    #pragma unroll
    for (int c = 0; c < NC; ++c) acc[c] = (f32x4){0.f,0.f,0.f,0.f};
    #pragma unroll 4
    for (int i = 0; i < 16; ++i) {
        f32x4 a = *(const f32x4*)ap;  ap += 32 * 64;
        #pragma unroll
        for (int g = 0; g < NC / 4; ++g) {
            f32x4 w = *(const f32x4*)(wp + 4 * g);
            F4(acc[4*g+0],w.x) F4(acc[4*g+1],w.y) F4(acc[4*g+2],w.z) F4(acc[4*g+3],w.w)
        }
        wp += 32 * 12;
    }
    #pragma unroll
    for (int c = 0; c < NC; ++c) {
        f32x4 v = acc[c];
        v.x += __shfl_xor(v.x,16); v.y += __shfl_xor(v.y,16);
        v.z += __shfl_xor(v.z,16); v.w += __shfl_xor(v.w,16);
        v.x += __shfl_xor(v.x,32); v.y += __shfl_xor(v.y,32);
        v.z += __shfl_xor(v.z,32); v.w += __shfl_xor(v.w,32);
        if (ln < 16) *(f32x4*)&red[(wv * NC + c) * 64 + (ln << 2)] = v;
    }
    __syncthreads();
    if (tid < NC * 64) {
        int c = tid >> 6, b = tid & 63;
        float s = bias_l[C0 + c];
        #pragma unroll
        for (int w = 0; w < 8; ++w) s += red[(w * NC + c) * 64 + b];
        dst[(C0 + c) * 64 + b] = s;
    }
}

// global barrier wait: wave 0 polls all 64 counters in parallel, __all exit
__device__ __forceinline__ void gbar_wait(int slot, int tid) {
    if (tid < 64) {
        for (;;) {
            unsigned c = __hip_atomic_load(&g_bar[slot][tid << 5],
                                           __ATOMIC_RELAXED, __HIP_MEMORY_SCOPE_AGENT);
            if (__all(c >= 4u)) break;
            __builtin_amdgcn_s_sleep(1);
        }
    }
    __syncthreads();
    asm volatile("" ::: "memory");
}

// ---------------- persistent recurrence kernel ------------------------------
// 256 blocks x 512 threads; block owns hidden cols j = 4*blk..+3.
// P1 h_hat (fused coherent publish) | arrive A | gi cols 0-7 | wait A |
// P2 gh + gates (fused h publish) | arrive B | out-write + gi cols 8-11 |
// wait B.
__launch_bounds__(NTHR, 1)
__global__ void skipgru_2ph(const float* __restrict__ Wlin, const float* __restrict__ Wih,
                            const float* __restrict__ bih,  const float* __restrict__ Whh,
                            const float* __restrict__ bhh,  float* __restrict__ out) {
    __shared__ float wA[H_ * 4];        // 16 KB [k][c<4]
    __shared__ float wB[H_ * 12];       // 48 KB [k][c<12]
    __shared__ float wX[IN_ * 12];      // 24 KB [k][c<12]
    __shared__ float red[8 * 12 * 64];  // 24 KB
    __shared__ float gh_l[12 * 64];
    __shared__ float gi_a[12 * 64];
    __shared__ float gi_b[12 * 64];
    __shared__ float hh_l[4 * 64];
    __shared__ float hn_l[4 * 64];
    __shared__ float zp_l[4 * 64];
    __shared__ float bhh_l[12];
    __shared__ float bih_l[12];

    const int tid = threadIdx.x;
    const int jb  = blockIdx.x << 2;
    const int bq  = tid & 15;
    const int kq  = tid >> 4;
    const int wv  = tid >> 6, ln = tid & 63;
    const int barctr = (blockIdx.x & 63) << 5;   // 64 counters, 128 B apart

    for (int c = 0; c < 4; ++c) {
        const float* src = Wlin + (size_t)(jb + c) * WLK_;
        for (int k = tid; k < H_; k += NTHR) wA[k * 4 + c] = src[k];
    }
    for (int c = 0; c < 12; ++c) {
        const float* src = Whh + (size_t)((c >> 2) * H_ + jb + (c & 3)) * H_;
        for (int k = tid; k < H_; k += NTHR) wB[k * 12 + c] = src[k];
    }
    for (int c = 0; c < 12; ++c) {
        const float* src = Wih + (size_t)((c >> 2) * H_ + jb + (c & 3)) * IN_;
        for (int k = tid; k < IN_; k += NTHR) wX[k * 12 + c] = src[k];
    }
    if (tid < 256) zp_l[tid] = g_zprojT[(jb + (tid >> 6)) * 64 + (tid & 63)];
    if (tid < 12) {
        bhh_l[tid] = bhh[(tid >> 2) * H_ + jb + (tid & 3)];
        bih_l[tid] = bih[(tid >> 2) * H_ + jb + (tid & 3)];
    }
    __syncthreads();

    gemm12n(g_xT, wX, bih_l, gi_a, red, tid);
    __syncthreads();

    const i32x4 rs_hhat = mkrsrc(g_hhatT);
    const i32x4 rs_h0   = mkrsrc(g_h0T);
    const i32x4 rs_ha   = mkrsrc(g_hT[0]);
    const i32x4 rs_hb   = mkrsrc(g_hT[1]);

    for (int t = 0; t < S_; ++t) {
        const i32x4 rs_h = (t == 0) ? rs_h0 : ((t & 1) ? rs_hb : rs_ha);
        const float* gi_cur = (t & 1) ? gi_b : gi_a;
        float*       gi_nxt = (t & 1) ? gi_a : gi_b;
        const float* xnxt = g_xT + (size_t)(t + 1) * IN_ * B_;

        // ---- P1: h_hat, 4 cols, K=1024 (16B sc1 coherent loads, unroll 8) ----
        {
            int voff = ((kq << 6) + (bq << 2)) << 2;
            const float* wp = wA + kq * 4;
            f32x4 acc[4];
            #pragma unroll
            for (int c = 0; c < 4; ++c) acc[c] = (f32x4){0.f,0.f,0.f,0.f};
            #pragma unroll 8
            for (int i = 0; i < 32; ++i) {
                f32x4 a = llvm_amdgcn_raw_buffer_load_v4f32(rs_h, voff, 0, 16);
                voff += 8192;
                f32x4 w = *(const f32x4*)wp;  wp += 32 * 4;
                F4(acc[0],w.x) F4(acc[1],w.y) F4(acc[2],w.z) F4(acc[3],w.w)
            }
            #pragma unroll
            for (int c = 0; c < 4; ++c) {
                f32x4 v = acc[c];
                v.x += __shfl_xor(v.x,16); v.y += __shfl_xor(v.y,16);
                v.z += __shfl_xor(v.z,16); v.w += __shfl_xor(v.w,16);
                v.x += __shfl_xor(v.x,32); v.y += __shfl_xor(v.y,32);
                v.z += __shfl_xor(v.z,32); v.w += __shfl_xor(v.w,32);
                if (ln < 16) *(f32x4*)&red[(wv * 4 + c) * 64 + (ln << 2)] = v;
            }
        }
        __syncthreads();
        if (tid < 256) {   // fused: compute + LDS + coherent publish (4B)
            int c = tid >> 6, b = tid & 63;
            float s = zp_l[tid];
            #pragma unroll
            for (int w = 0; w < 8; ++w) s += red[(w * 4 + c) * 64 + b];
            hh_l[tid] = s;
            coh_store1(&g_hhatT[(jb + c) * 64 + b], s);
        }
        __syncthreads();   // vmcnt(0) drain: h_hat publish complete before arrive

        // ---- arrive A ----
        if (tid == 0)
            __hip_atomic_fetch_add(&g_bar[2 * t][barctr], 1u, __ATOMIC_RELAXED, __HIP_MEMORY_SCOPE_AGENT);

        // ---- gi(t+1) cols 0-7, hidden under barrier A ----
        if (t + 1 < S_)
            gemmN<8, 0>(xnxt, wX, bih_l, gi_nxt, red, tid);

        // ---- wait A ----
        gbar_wait(2 * t, tid);

        // ---- P2: gh, 12 cols over h_hat, K=1024 (16B sc1, unroll 8) ----
        gemm12b(rs_hhat, wB, bhh_l, gh_l, red, tid);
        __syncthreads();

        // ---- gates + fused h publish (threads 0..255) ----
        if (tid < 256) {
            int cc = tid >> 6, b = tid & 63;
            float hh = hh_l[tid];
            float hr = gh_l[cc * 64 + b];
            float hz = gh_l[(4 + cc) * 64 + b];
            float hn = gh_l[(8 + cc) * 64 + b];
            float ir = gi_cur[cc * 64 + b];
            float iz = gi_cur[(4 + cc) * 64 + b];
            float in_ = gi_cur[(8 + cc) * 64 + b];
            float r = 1.f / (1.f + expf(-(ir + hr)));
            float u = 1.f / (1.f + expf(-(iz + hz)));
            float n = tanhf(in_ + r * hn);
            float v = (1.f - u) * n + u * hh;
            hn_l[tid] = v;
            coh_store1(&g_hT[(t + 1) & 1][(jb + cc) * 64 + b], v);
        }
        __syncthreads();   // vmcnt(0) drain: h publish complete before arrive

        // ---- arrive B ----
        if (tid == 0)
            __hip_atomic_fetch_add(&g_bar[2 * t + 1][barctr], 1u, __ATOMIC_RELAXED, __HIP_MEMORY_SCOPE_AGENT);

        // ---- out write + gi(t+1) cols 8-11, hidden under barrier B ----
        if (tid < 256) {
            int cc = tid >> 6, b = tid & 63;
            int j = jb + cc;
            float v = hn_l[tid];
            out[((size_t)b * S_ + t) * H_ + j] = v;
            if (t == S_ - 1)
                out[(size_t)B_ * S_ * H_ + (size_t)b * H_ + j] = v;
        }
        if (t + 1 < S_)
            gemmN<4, 8>(xnxt, wX, bih_l, gi_nxt, red, tid);

        // ---- wait B ----
        gbar_wait(2 * t + 1, tid);
    }
}

extern "C" void kernel_launch(void* const* d_in, const int* in_sizes, int n_in,
                              void* d_out, int out_size, void* d_ws, size_t ws_size,
                              hipStream_t stream) {
    const float* inputs = (const float*)d_in[0];
    const float* h0     = (const float*)d_in[1];
    const float* z      = (const float*)d_in[2];
    const float* Wlin   = (const float*)d_in[3];
    const float* blin   = (const float*)d_in[4];
    const float* Wih    = (const float*)d_in[5];
    const float* bih    = (const float*)d_in[6];
    const float* Whh    = (const float*)d_in[7];
    const float* bhh    = (const float*)d_in[8];
    float* out = (float*)d_out;

    hipLaunchKernelGGL(pre_transpose_x, dim3(S_ * 8), dim3(256), 0, stream, inputs);
    hipLaunchKernelGGL(pre_misc, dim3(H_), dim3(64), 0, stream, z, Wlin, blin, h0);
    hipLaunchKernelGGL(skipgru_2ph, dim3(NBLK), dim3(NTHR), 0, stream,
                       Wlin, Wih, bih, Whh, bhh, out);
}